// Round 11
// baseline (163.530 us; speedup 1.0000x reference)
//
#include <hip/hip_runtime.h>

// Problem constants (match reference)
constexpr int T     = 4;
constexpr int NROWS = 1000000;
constexpr int B     = 16384;
constexpr int TOTAL = 16384 * 50; // 819200 lookups per table

typedef float    fv4 __attribute__((ext_vector_type(4)));
typedef int      iv2 __attribute__((ext_vector_type(2)));
typedef _Float16 h2  __attribute__((ext_vector_type(2)));

// ws layout: p[T*NROWS] _Float16 (8 MB) at offset 0; dummy sink at ws_size/2.

// ========================== DIAGNOSTIC ROUND 11 ==========================
// Pool has NEVER crossed the top-5 visibility cutoff (~41 µs) in 10 rounds —
// its duration/FETCH/VALUBusy have only ever been inferred. All pool theories
// since r7 (traffic: r5; MLP: r3/r8; L1-bypass NT: r10, −21 µs) are refuted.
// This round triples the pool body in ONE dispatch (passes 1-2 -> dummy sink,
// shifted stream positions so loads/gathers are real and distinct) to force
// it into the top-5 WITH counters, and to measure marginal cost = dtotal/2.
// Pass 0 is bit-identical to r7's pool => correctness unchanged.
// =========================================================================

// Producer (r5/r7 proven; r6 double-pass diag: ~at its 72 MB BW floor).
__global__ __launch_bounds__(256)
void produce_kernel(const fv4*   __restrict__ tables,
                    const float* __restrict__ Wp,
                    const float* __restrict__ bias,
                    h2*          __restrict__ p2,     // [T*NROWS/2]
                    float*       __restrict__ out) {
    const int i = blockIdx.x * 256 + threadIdx.x;     // pair index [0, 2M)
    if (i < T * NROWS / 2) {
        const float wx = Wp[0], wy = Wp[1], wz = Wp[2], ww = Wp[3];
        const fv4 a = tables[2 * i];
        const fv4 b = tables[2 * i + 1];
        const float pa = a.x * wx + a.y * wy + a.z * wz + a.w * ww;
        const float pb = b.x * wx + b.y * wy + b.z * wz + b.w * ww;
        h2 h; h.x = (_Float16)pa; h.y = (_Float16)pb;
        p2[i] = h;
    }
    if (i < T * B) out[i] = bias[0];
}

// --- wave64 inclusive +scan via DPP: 6 VALU ops, no LDS (r7 proven).
template<int CTRL, int ROW_MASK, int BANK_MASK>
__device__ __forceinline__ float dpp_add(float x) {
    const int t = __builtin_amdgcn_update_dpp(0, __float_as_int(x),
                                              CTRL, ROW_MASK, BANK_MASK, true);
    return x + __int_as_float(t);
}
__device__ __forceinline__ float wave64_incl_scan(float x) {
    x = dpp_add<0x111, 0xf, 0xf>(x);   // row_shr:1
    x = dpp_add<0x112, 0xf, 0xf>(x);   // row_shr:2
    x = dpp_add<0x114, 0xf, 0xf>(x);   // row_shr:4
    x = dpp_add<0x118, 0xf, 0xf>(x);   // row_shr:8
    x = dpp_add<0x142, 0xa, 0xf>(x);   // row_bcast:15 -> rows 1,3
    x = dpp_add<0x143, 0xc, 0xf>(x);   // row_bcast:31 -> rows 2,3
    return x;
}

// Pool = r7 body, run 3x. rep 0: real (out). reps 1,2: shifted stream chunk
// (distinct addresses -> compiler cannot CSE the loads; same distribution),
// flushed to dummy. Cached streams (r7 win), CACHED gathers (r10: NT on
// gathers -21 us — nt demotes L2+L3 allocation on gfx950, destroying the
// ~13x/line reuse). XCD pinning: table t -> XCD pair {2t,2t+1}.
__global__ __launch_bounds__(256)
void pool_kernel(const _Float16* __restrict__ p,       // [T*NROWS] fp16
                 const iv2*      __restrict__ indices, // [T*TOTAL/2]
                 const iv2*      __restrict__ segids,  // [T*TOTAL/2] sorted/table
                 float*          __restrict__ out,     // [T*B], pre-set to bias
                 float*          __restrict__ dummy)   // [T*B] sink in ws
{
    const int xcd    = blockIdx.x & 7;
    const int t      = xcd >> 1;
    const int within = ((blockIdx.x >> 3) << 1) + (xcd & 1);   // [0, 1600)
    const int q      = within * 256 + threadIdx.x;             // [0, 409600)
    const int lane   = threadIdx.x & 63;
    const _Float16* pt = p + t * NROWS;

    constexpr int QT    = TOTAL / 2;                   // 409600 pairs per table
    constexpr int SHIFT = 136533;                      // ~QT/3

    #pragma unroll 1
    for (int rep = 0; rep < 3; ++rep) {
        int qq = q + rep * SHIFT;                      // max < 2*QT
        if (qq >= QT) qq -= QT;
        const int gq = t * QT + qq;
        float* outt = (rep == 0 ? out : dummy) + t * B;

        const iv2 s2 = segids[gq];                     // cached, coalesced
        const iv2 i2 = indices[gq];

        const float v0 = (float)pt[i2.x];              // cached gathers
        const float v1 = (float)pt[i2.y];
        const int   s0 = s2.x, s1 = s2.y;

        // In-lane pair combine: x = sum of this lane's tail-run elements.
        const float a0 = v0;
        const float x  = v1 + (s1 == s0 ? v0 : 0.f);
        const int   key = s1;

        // Unsegmented DPP scan; segmentation by prefix differences.
        const float P = wave64_incl_scan(x);
        const float E = P - x;                         // P[lane-1]

        const int kprev = __shfl_up(key, 1, 64);
        const int snext = __shfl_down(s0, 1, 64);
        const bool head = (lane == 0) || (kprev != key);
        const unsigned long long mask = __ballot(head);

        const unsigned long long le = mask & (~0ULL >> (63 - lane));
        const int   F  = 63 - __builtin_clzll(le);
        const float Ef = __shfl(E, F, 64);             // P[F-1]

        const unsigned long long lt = lane ? (mask & (~0ULL >> (64 - lane))) : 1ULL;
        const int   Fp  = 63 - __builtin_clzll(lt);
        const float Efp = __shfl(E, Fp, 64);           // P[F'-1]

        // Internal-boundary flush: seg s0 ends at this lane's element 0.
        if (s0 != s1) {
            const float carry = (lane > 0 && kprev == s0) ? (E - Efp) : 0.f;
            atomicAdd(&outt[s0], a0 + carry);
        }
        // Tail flush: last lane of each tail-key run.
        if (lane == 63 || snext != key) {
            atomicAdd(&outt[key], P - Ef);
        }
    }
}

extern "C" void kernel_launch(void* const* d_in, const int* in_sizes, int n_in,
                              void* d_out, int out_size, void* d_ws, size_t ws_size,
                              hipStream_t stream) {
    const fv4*   tables  = (const fv4*)d_in[0];      // [T, N, 4] f32
    const float* W       = (const float*)d_in[1];    // [1, 4]   f32
    const float* bias    = (const float*)d_in[2];    // [1]      f32
    const iv2*   indices = (const iv2*)d_in[3];      // [T, TOTAL]
    const iv2*   segids  = (const iv2*)d_in[4];      // [T, TOTAL] sorted per table
    float*       out     = (float*)d_out;            // [T*B] f32

    h2*       p2 = (h2*)d_ws;                        // 8 MB fp16 scratch
    _Float16* p  = (_Float16*)d_ws;
    // Dummy sink for diagnostic passes 1-2: upper half of ws (>= 8MB + slack).
    float*    dummy = (float*)((char*)d_ws + ws_size / 2);

    {
        int n = T * NROWS / 2;                       // 2,000,000 pairs -> 7813 blocks
        produce_kernel<<<(n + 255) / 256, 256, 0, stream>>>(tables, W, bias, p2, out);
    }
    {
        // T*TOTAL/2 = 1,638,400 threads = 6,400 blocks (multiple of 8 for pinning)
        pool_kernel<<<6400, 256, 0, stream>>>(p, indices, segids, out, dummy);
    }
}

// Round 12
// 131.466 us; speedup vs baseline: 1.2439x; 1.2439x over previous
//
#include <hip/hip_runtime.h>

// Problem constants (match reference)
constexpr int T     = 4;
constexpr int NROWS = 1000000;
constexpr int B     = 16384;
constexpr int TOTAL = 16384 * 50; // 819200 lookups per table

typedef float    fv4 __attribute__((ext_vector_type(4)));
typedef int      iv2 __attribute__((ext_vector_type(2)));
typedef _Float16 h2  __attribute__((ext_vector_type(2)));

// ws layout: p[T*NROWS] _Float16 (8 MB). fp16 quantization err ~3.5e-5
// accumulated << the ~1e-3 tolerance measured passing since r5.
//
// ====================== FINAL FORM (r7, best measured) ======================
// Session evidence ledger:
//  - fixed harness ≈ 89 µs (poison fill 41 µs @81% HBM peak + restores).
//  - produce ≈ 10 µs: at its 72 MB BW floor (r6 idempotent-double-pass diag:
//    marginal pass +7 µs).
//  - pool ≈ 17-20 µs: at the DIVERGENT-GATHER TRANSACTION-RATE floor. r11
//    tripled-pool diag exposed counters: VALUBusy 13%, HBM 11% — neither pipe
//    saturated; 3.28M random 2B lookups = 3.28M mandatory line transactions
//    (random idx => no line sharing) at measured ~0.31 trans/cy/CU.
//    Refuted levers: traffic /2 (r5 neutral), MLP x2/x8 (r3/r8 neutral/worse),
//    L1-bypass NT gathers (r10 −21 µs), direct 16B gathers (r2 +24 µs),
//    grid-sync fusion (r4 +150 µs).
// ===========================================================================

// Producer: p[t*NROWS+r] = dot(table[t][r], W), 2 rows/thread, packed h2
// store. Cached table loads (r1: NT regresses — tables are L3-warm).
// Fused out[:] = bias init (pool's atomics accumulate on top).
__global__ __launch_bounds__(256)
void produce_kernel(const fv4*   __restrict__ tables,
                    const float* __restrict__ Wp,
                    const float* __restrict__ bias,
                    h2*          __restrict__ p2,     // [T*NROWS/2]
                    float*       __restrict__ out) {
    const int i = blockIdx.x * 256 + threadIdx.x;     // pair index [0, 2M)
    if (i < T * NROWS / 2) {
        const float wx = Wp[0], wy = Wp[1], wz = Wp[2], ww = Wp[3];
        const fv4 a = tables[2 * i];
        const fv4 b = tables[2 * i + 1];
        const float pa = a.x * wx + a.y * wy + a.z * wz + a.w * ww;
        const float pb = b.x * wx + b.y * wy + b.z * wz + b.w * ww;
        h2 h; h.x = (_Float16)pa; h.y = (_Float16)pb;
        p2[i] = h;
    }
    if (i < T * B) out[i] = bias[0];
}

// --- wave64 inclusive +scan via DPP: 6 VALU ops, no LDS.
template<int CTRL, int ROW_MASK, int BANK_MASK>
__device__ __forceinline__ float dpp_add(float x) {
    const int t = __builtin_amdgcn_update_dpp(0, __float_as_int(x),
                                              CTRL, ROW_MASK, BANK_MASK, true);
    return x + __int_as_float(t);
}
__device__ __forceinline__ float wave64_incl_scan(float x) {
    x = dpp_add<0x111, 0xf, 0xf>(x);   // row_shr:1
    x = dpp_add<0x112, 0xf, 0xf>(x);   // row_shr:2
    x = dpp_add<0x114, 0xf, 0xf>(x);   // row_shr:4
    x = dpp_add<0x118, 0xf, 0xf>(x);   // row_shr:8
    x = dpp_add<0x142, 0xa, 0xf>(x);   // row_bcast:15 -> rows 1,3
    x = dpp_add<0x143, 0xc, 0xf>(x);   // row_bcast:31 -> rows 2,3
    return x;
}

// Pool: 2 lookups/thread, cached coalesced streams (r7 win vs NT), CACHED
// gathers (r10: NT gathers −21 µs), unsegmented DPP scan + algebraic
// segmentation via prefix differences (r7 win: removed the 12-deep serial
// ds_bpermute chain), 1-2 atomics per seg run. XCD-pinned: table t -> XCD
// pair {2t,2t+1}; 2 MB fp16 p slice resident in each 4 MiB L2.
__global__ __launch_bounds__(256)
void pool_kernel(const _Float16* __restrict__ p,       // [T*NROWS] fp16
                 const iv2*      __restrict__ indices, // [T*TOTAL/2]
                 const iv2*      __restrict__ segids,  // [T*TOTAL/2] sorted/table
                 float*          __restrict__ out)     // [T*B], pre-set to bias
{
    const int xcd    = blockIdx.x & 7;
    const int t      = xcd >> 1;
    const int within = ((blockIdx.x >> 3) << 1) + (xcd & 1);   // [0, 1600)
    const int q      = within * 256 + threadIdx.x;             // pair idx
    const int gq     = t * (TOTAL / 2) + q;
    const int lane   = threadIdx.x & 63;

    const iv2 s2 = segids[gq];          // cached: L3-warm, coalesced
    const iv2 i2 = indices[gq];

    const _Float16* pt = p + t * NROWS;
    const float v0 = (float)pt[i2.x];   // cached gathers (L2-resident slice)
    const float v1 = (float)pt[i2.y];
    const int   s0 = s2.x, s1 = s2.y;

    // In-lane pair combine: x = sum of this lane's elements in its TAIL run.
    const float a0 = v0;
    const float x  = v1 + (s1 == s0 ? v0 : 0.f);
    const int   key = s1;

    // Unsegmented inclusive scan P, exclusive E = P - x (pure VALU).
    const float P = wave64_incl_scan(x);
    const float E = P - x;              // = P[lane-1]

    // Head flags over tail-keys (sorted => equal keys contiguous).
    const int kprev = __shfl_up(key, 1, 64);
    const int snext = __shfl_down(s0, 1, 64);
    const bool head = (lane == 0) || (kprev != key);
    const unsigned long long mask = __ballot(head);

    // F  = start lane of MY tail-key run (highest head <= lane).
    const unsigned long long le = mask & (~0ULL >> (63 - lane));
    const int   F  = 63 - __builtin_clzll(le);
    const float Ef = __shfl(E, F, 64);                 // P[F-1]

    // F' = start lane of the run ending at lane-1 (for the internal carry).
    const unsigned long long lt = lane ? (mask & (~0ULL >> (64 - lane))) : 1ULL;
    const int   Fp  = 63 - __builtin_clzll(lt);
    const float Efp = __shfl(E, Fp, 64);               // P[F'-1]

    float* outt = out + t * B;

    // Internal-boundary flush: seg s0 ends at this lane's element 0.
    if (s0 != s1) {
        const float carry = (lane > 0 && kprev == s0) ? (E - Efp) : 0.f;
        atomicAdd(&outt[s0], a0 + carry);
    }

    // Tail flush: last lane of each tail-key run; run sum = P - P[F-1].
    if (lane == 63 || snext != key) {
        atomicAdd(&outt[key], P - Ef);
    }
}

extern "C" void kernel_launch(void* const* d_in, const int* in_sizes, int n_in,
                              void* d_out, int out_size, void* d_ws, size_t ws_size,
                              hipStream_t stream) {
    const fv4*   tables  = (const fv4*)d_in[0];      // [T, N, 4] f32
    const float* W       = (const float*)d_in[1];    // [1, 4]   f32
    const float* bias    = (const float*)d_in[2];    // [1]      f32
    const iv2*   indices = (const iv2*)d_in[3];      // [T, TOTAL]
    const iv2*   segids  = (const iv2*)d_in[4];      // [T, TOTAL] sorted per table
    float*       out     = (float*)d_out;            // [T*B] f32

    h2*       p2 = (h2*)d_ws;                        // 8 MB fp16 scratch
    _Float16* p  = (_Float16*)d_ws;

    {
        int n = T * NROWS / 2;                       // 2,000,000 pairs -> 7813 blocks
        produce_kernel<<<(n + 255) / 256, 256, 0, stream>>>(tables, W, bias, p2, out);
    }
    {
        // T*TOTAL/2 = 1,638,400 threads = 6,400 blocks (multiple of 8 for pinning)
        pool_kernel<<<6400, 256, 0, stream>>>(p, indices, segids, out);
    }
}